// Round 5
// baseline (1460.050 us; speedup 1.0000x reference)
//
#include <hip/hip_runtime.h>

typedef _Float16 half8 __attribute__((ext_vector_type(8)));
typedef float floatx4 __attribute__((ext_vector_type(4)));

#define T_STEPS 20
#define NSEQ 131072
#define HID 192
#define ROWS 32
#define HPAD 200            // fp16 elems per LDS h-row; cols 192..194 = [x.x, x.y, 1]
#define HROWS 17            // 16 rows + zero guard row (kc6 quad over-read)
#define WOFF 147456         // frags: wout section      (3072 halfs)
#define XOFF 150528         // frags: w_ih/bias section (6144 halfs, compact q==0 layout)
#define FR_TOTAL (XOFF + 6144)

#define MFMA16(a, b, c) __builtin_amdgcn_mfma_f32_16x16x32_f16((a), (b), (c), 0, 0, 0)

// Rewrite w_hh / w_out / (w_ih,b) into MFMA B-fragment order (fp16).
// B-frag 16x16x32: lane L = q*16 + n holds k = q*8..q*8+7 of column n.
// W_hh section: [12 ht][6 kc][4 g][64 lanes][8 e]
// WX section:   [12 ht][4 g][16 n][8 e] compact — only the q==0 rows (k<8):
//               e0 = w_ih[col][0], e1 = w_ih[col][1], e2 = b_ih[col]+b_hh[col], e3..7 = 0
__global__ void build_frags(const float* __restrict__ whh,
                            const float* __restrict__ wout,
                            const float* __restrict__ wih,
                            const float* __restrict__ bih,
                            const float* __restrict__ bhh,
                            _Float16* __restrict__ dst) {
    int i = blockIdx.x * 256 + threadIdx.x;
    if (i < WOFF) {
        int e = i & 7, L = (i >> 3) & 63, g = (i >> 9) & 3, u = i >> 11;
        int kc = u % 6, ht = u / 6;
        int n = L & 15, q = L >> 4;
        dst[i] = (_Float16)whh[(size_t)(g * HID + ht * 16 + n) * HID + kc * 32 + q * 8 + e];
    } else if (i < XOFF) {
        int k = i - WOFF;
        int e = k & 7, L = (k >> 3) & 63, kc = k >> 9;
        int n = L & 15, q = L >> 4;
        dst[i] = (_Float16)((n < 2) ? wout[n * HID + kc * 32 + q * 8 + e] : 0.f);
    } else if (i < FR_TOTAL) {
        int k = i - XOFF;
        int e = k & 7, n = (k >> 3) & 15, g = (k >> 7) & 3, ht = k >> 9;
        int col = g * HID + ht * 16 + n;
        float v = 0.f;
        if (e == 0)      v = wih[col * 2];
        else if (e == 1) v = wih[col * 2 + 1];
        else if (e == 2) v = bih[col] + bhh[col];
        dst[i] = (_Float16)v;
    }
}

// 768 threads = 12 waves, 1 block/CU (LDS ~130 KB). Skewed two-half schedule;
// instruction-level MFMA/VALU interleave via sched_group_barrier. Round-5
// change: LDS reads inside build are software-pipelined 1-2 units ahead of
// their consuming MFMA quartet (round 3's SGB pattern forced read-adjacent-
// to-use, exposing ~120 cyc LDS latency per quartet -> MfmaUtil capped ~35%).
__global__ __launch_bounds__(768) __attribute__((amdgpu_waves_per_eu(3, 3)))
void lstm_fused_kernel(
    const float* __restrict__ obs,       // [20][N][2]
    const float* __restrict__ h0,        // [N][192]
    const float* __restrict__ b_out,     // [2]
    const _Float16* __restrict__ frags,  // whh + wout + wx fragments (fp16)
    float* __restrict__ out)             // [20][N][2]
{
    __shared__ _Float16 h0b[2][HROWS][HPAD];  // rows 0..15, double-buffered (13600 B)
    __shared__ _Float16 h1b[HROWS][HPAD];     // rows 16..31, single-buffered (6800 B)
    __shared__ _Float16 b_lds[49152];         // whh kc4,kc5: [12ht][2][4g][512] (98304 B)
    __shared__ _Float16 wo_lds[3072];         // wout frags (6144 B)
    __shared__ float2 x_all[T_STEPS][ROWS];   // all steps' x (5120 B)

    const int tid  = threadIdx.x;
    const int wave = tid >> 6;
    const int lane = tid & 63;
    const int quad = lane >> 4;
    const int l16  = lane & 15;
    const int ht   = wave;
    const int base = blockIdx.x * ROWS;
    const int j    = ht * 16 + l16;

    const half8 HZ = {0, 0, 0, 0, 0, 0, 0, 0};

    // ---- resident weights: whh kc0..3 B-frags (64 VGPRs) + kc6 x/bias (16) ----
    half8 bw[16], bx[4];
#pragma unroll
    for (int kc = 0; kc < 4; ++kc)
#pragma unroll
        for (int g = 0; g < 4; ++g)
            bw[kc * 4 + g] = *(const half8*)&frags[(((ht * 6 + kc) * 4 + g) << 9) + lane * 8];
#pragma unroll
    for (int g = 0; g < 4; ++g)
        bx[g] = (quad == 0)
              ? *(const half8*)&frags[XOFF + ht * 512 + g * 128 + l16 * 8]
              : HZ;   // quads 1..3 contribute zero (their A over-read is nulled)

    // ---- staging phase A: zero h-buffers, stage kc4-5 / wout / x ----
    for (int i = tid; i < 2 * HROWS * HPAD / 8; i += 768) ((half8*)h0b)[i] = HZ;
    for (int i = tid; i < HROWS * HPAD / 8; i += 768)     ((half8*)h1b)[i] = HZ;
    for (int i = tid; i < 6144; i += 768) {   // b_lds <- whh kc4,kc5
        int g = (i >> 6) & 3, u = i >> 8, k2 = u & 1, h = u >> 1;
        ((half8*)b_lds)[i] = *(const half8*)&frags[(((h * 6 + 4 + k2) * 4 + g) << 9) + (i & 63) * 8];
    }
    if (tid < 384) ((half8*)wo_lds)[tid] = *(const half8*)&frags[WOFF + tid * 8];
    if (tid < T_STEPS * ROWS) {
        int t = tid >> 5, r = tid & 31;
        int src = (t == 0) ? 0 : (t - 1);
        x_all[t][r] = *(const float2*)&obs[((size_t)src * NSEQ + base + r) * 2];
    }
    __syncthreads();

    // ---- staging phase B: h0 -> fp16 rows; x_0; the '1' column ----
    for (int i = tid; i < ROWS * HID / 4; i += 768) {
        float4 v = *(const float4*)&h0[(size_t)base * HID + i * 4];
        int row = (i * 4) / HID, k = i * 4 - row * HID;
        _Float16* d = (row < 16) ? &h0b[0][row][k] : &h1b[row - 16][k];
        d[0] = (_Float16)v.x; d[1] = (_Float16)v.y;
        d[2] = (_Float16)v.z; d[3] = (_Float16)v.w;
    }
    if (tid < 64) {
        int row = tid >> 1;
        _Float16 v = (_Float16)((const float*)x_all[0])[tid];
        if (row < 16) h0b[0][row][192 + (tid & 1)] = v;
        else          h1b[row - 16][192 + (tid & 1)] = v;
    }
    if (tid < 16)      { h0b[0][tid][194] = (_Float16)1.f; h0b[1][tid][194] = (_Float16)1.f; }
    else if (tid < 32)   h1b[tid - 16][194] = (_Float16)1.f;
    __syncthreads();

    const float bo_n = (l16 < 2) ? b_out[l16] : 0.f;

    float c[8];
#pragma unroll
    for (int i = 0; i < 8; ++i) c[i] = 0.f;

    // gate MFMAs for one 16-row half, reads software-pipelined 1-2 units
    // ahead of the consuming quartet (matches sched_pattern's read groups):
    //   upfront: ax,a0 | u1:+a1 | u2:+a2 | u3:+a3 | u4:+a4,b40,b41
    //   u5:+a5,b42,b43 | u6:+b50..b53 | u7: none
    auto build = [&](const _Float16* hb, floatx4* aN) {
        const _Float16* ar = hb + l16 * HPAD;
        const _Float16* blp = b_lds;
        asm volatile("" : "+v"(blp));     // defeat LICM of the b-frag ds_reads
#pragma unroll
        for (int g = 0; g < 4; ++g) aN[g] = (floatx4){0.f, 0.f, 0.f, 0.f};

        half8 ax = *(const half8*)(ar + 192 + quad * 8);   // quads 1-3 over-read: B=0
        half8 a0 = *(const half8*)(ar + 0 * 32 + quad * 8);
        // u1
        half8 a1 = *(const half8*)(ar + 1 * 32 + quad * 8);
#pragma unroll
        for (int g = 0; g < 4; ++g) aN[g] = MFMA16(ax, bx[g], aN[g]);
        // u2
        half8 a2 = *(const half8*)(ar + 2 * 32 + quad * 8);
#pragma unroll
        for (int g = 0; g < 4; ++g) aN[g] = MFMA16(a0, bw[g], aN[g]);
        // u3
        half8 a3 = *(const half8*)(ar + 3 * 32 + quad * 8);
#pragma unroll
        for (int g = 0; g < 4; ++g) aN[g] = MFMA16(a1, bw[4 + g], aN[g]);
        // u4
        half8 a4  = *(const half8*)(ar + 4 * 32 + quad * 8);
        half8 b40 = *(const half8*)&blp[(((ht * 2 + 0) * 4 + 0) << 9) + lane * 8];
        half8 b41 = *(const half8*)&blp[(((ht * 2 + 0) * 4 + 1) << 9) + lane * 8];
#pragma unroll
        for (int g = 0; g < 4; ++g) aN[g] = MFMA16(a2, bw[8 + g], aN[g]);
        // u5
        half8 a5  = *(const half8*)(ar + 5 * 32 + quad * 8);
        half8 b42 = *(const half8*)&blp[(((ht * 2 + 0) * 4 + 2) << 9) + lane * 8];
        half8 b43 = *(const half8*)&blp[(((ht * 2 + 0) * 4 + 3) << 9) + lane * 8];
#pragma unroll
        for (int g = 0; g < 4; ++g) aN[g] = MFMA16(a3, bw[12 + g], aN[g]);
        // u6
        half8 b50 = *(const half8*)&blp[(((ht * 2 + 1) * 4 + 0) << 9) + lane * 8];
        half8 b51 = *(const half8*)&blp[(((ht * 2 + 1) * 4 + 1) << 9) + lane * 8];
        half8 b52 = *(const half8*)&blp[(((ht * 2 + 1) * 4 + 2) << 9) + lane * 8];
        half8 b53 = *(const half8*)&blp[(((ht * 2 + 1) * 4 + 3) << 9) + lane * 8];
        aN[0] = MFMA16(a4, b40, aN[0]);
        aN[1] = MFMA16(a4, b41, aN[1]);
        aN[2] = MFMA16(a4, b42, aN[2]);
        aN[3] = MFMA16(a4, b43, aN[3]);
        // u7
        aN[0] = MFMA16(a5, b50, aN[0]);
        aN[1] = MFMA16(a5, b51, aN[1]);
        aN[2] = MFMA16(a5, b52, aN[2]);
        aN[3] = MFMA16(a5, b53, aN[3]);
    };

    // activation (rational form: 5 exp2 + 2 rcp per cell)
    auto act = [&](floatx4* aO, _Float16* hw, int cb) {
#pragma unroll
        for (int r = 0; r < 4; ++r) {
            const int row = quad * 4 + r;
            const float Ai = __builtin_amdgcn_exp2f(-1.4426950408889634f * aO[0][r]);
            const float Af = __builtin_amdgcn_exp2f(-1.4426950408889634f * aO[1][r]);
            const float Bg = __builtin_amdgcn_exp2f( 2.8853900817779268f * aO[2][r]);
            const float Co = __builtin_amdgcn_exp2f(-1.4426950408889634f * aO[3][r]);
            const float Qf = 1.f + Af;
            const float Pg = (1.f + Ai) * (Bg + 1.f);
            const float Nn = c[cb + r] * Pg + Qf * (Bg - 1.f);
            const float cn = Nn * __builtin_amdgcn_rcpf(Qf * Pg);
            c[cb + r] = cn;
            const float Dc = __builtin_amdgcn_exp2f(2.8853900817779268f * cn);
            const float hv = (Dc - 1.f) * __builtin_amdgcn_rcpf((1.f + Co) * (Dc + 1.f));
            hw[row * HPAD + j] = (_Float16)hv;
        }
    };

    // T19 pin, matching build's pipelined read layout. Reads lead their
    // consumers by >=1 unit (>=110 cyc in flight vs ~120 cyc LDS latency).
#define UNIT(nr, nv)                                              \
    do {                                                          \
        if (nr) __builtin_amdgcn_sched_group_barrier(0x100, nr, 0); \
        __builtin_amdgcn_sched_group_barrier(0x008, 4, 0);        \
        __builtin_amdgcn_sched_group_barrier(0x002, nv, 0);       \
    } while (0)
    auto sched_pattern = [&]() {
        __builtin_amdgcn_sched_group_barrier(0x100, 2, 0);   // ax, a0
        __builtin_amdgcn_sched_group_barrier(0x002, 8, 0);   // early act VALU
        UNIT(1, 10);   // u1: read a1   | MFMA(ax)
        UNIT(1, 10);   // u2: read a2   | MFMA(a0)
        UNIT(1, 10);   // u3: read a3   | MFMA(a1)
        UNIT(3, 10);   // u4: a4,b40,b41| MFMA(a2)
        UNIT(3, 10);   // u5: a5,b42,b43| MFMA(a3)
        UNIT(4, 10);   // u6: b50..b53  | MFMA(a4,b4x)
        UNIT(0, 10);   // u7:           | MFMA(a5,b5x)
        __builtin_amdgcn_sched_group_barrier(0x200, 4, 0);   // DS_WRITE (h)
    };

    // wout for one 16-row half (wave 0 -> rows 0..15, wave 1 -> rows 16..31)
    auto wout1 = [&](int ot, const _Float16* hbase) {
        const _Float16* ar = hbase + l16 * HPAD;
        floatx4 ao = {bo_n, bo_n, bo_n, bo_n};
#pragma unroll
        for (int kc = 0; kc < 6; ++kc) {
            half8 a = *(const half8*)(ar + kc * 32 + quad * 8);
            half8 b = *(const half8*)&wo_lds[kc * 512 + lane * 8];
            ao = MFMA16(a, b, ao);
        }
        if (l16 < 2) {
#pragma unroll
            for (int r = 0; r < 4; ++r)
                out[((size_t)ot * NSEQ + base + ht * 16 + quad * 4 + r) * 2 + l16] = ao[r];
        }
    };

    // ---- prologue: accA = gates for half0 at t=0 ----
    floatx4 accA[4], accB[4];
    build(&h0b[0][0][0], accA);

    for (int t = 0; t < T_STEPS - 1; ++t) {
        _Float16* h0n = &h0b[(t + 1) & 1][0][0];

        // ===== segment X: issue H1 gate MFMAs || activation(accA) -> next H0 =====
        build(&h1b[0][0], accB);
        act(accA, h0n, 0);
        sched_pattern();
        if (ht < 2 && t > 0)
            wout1(t - 1, (ht == 0) ? &h0b[t & 1][0][0] : &h1b[0][0]);
        if (ht == 11 && lane < 32)
            h0n[(lane >> 1) * HPAD + 192 + (lane & 1)] =
                (_Float16)((const float*)x_all[t + 1])[lane];
        __syncthreads();

        // ===== segment Y: issue next-H0 gate MFMAs || activation(accB) -> H1 =====
        build(h0n, accA);
        act(accB, &h1b[0][0], 4);
        sched_pattern();
        if (ht == 11 && lane < 32)
            h1b[lane >> 1][192 + (lane & 1)] =
                (_Float16)((const float*)x_all[t + 1])[32 + lane];
        __syncthreads();
    }

    // ---- t = 19 peeled ----
    build(&h1b[0][0], accB);
    act(accA, &h0b[0][0][0], 0);
    sched_pattern();
    if (ht < 2)
        wout1(18, (ht == 0) ? &h0b[1][0][0] : &h1b[0][0]);
    __syncthreads();
    act(accB, &h1b[0][0], 4);
    __syncthreads();
    if (ht < 2)
        wout1(19, (ht == 0) ? &h0b[0][0][0] : &h1b[0][0]);
}

extern "C" void kernel_launch(void* const* d_in, const int* in_sizes, int n_in,
                              void* d_out, int out_size, void* d_ws, size_t ws_size,
                              hipStream_t stream) {
    const float* obs  = (const float*)d_in[0];
    const float* h0   = (const float*)d_in[1];
    const float* wih  = (const float*)d_in[2];
    const float* whh  = (const float*)d_in[3];
    const float* bih  = (const float*)d_in[4];
    const float* bhh  = (const float*)d_in[5];
    const float* wout = (const float*)d_in[6];
    const float* bout = (const float*)d_in[7];
    float* out = (float*)d_out;
    _Float16* frags = (_Float16*)d_ws;   // 313344 B used

    build_frags<<<(FR_TOTAL + 255) / 256, 256, 0, stream>>>(whh, wout, wih, bih, bhh, frags);
    lstm_fused_kernel<<<NSEQ / ROWS, 768, 0, stream>>>(obs, h0, bout, frags, out);
}

// Round 6
// 1387.886 us; speedup vs baseline: 1.0520x; 1.0520x over previous
//
#include <hip/hip_runtime.h>

typedef _Float16 half8 __attribute__((ext_vector_type(8)));
typedef float floatx4 __attribute__((ext_vector_type(4)));

#define T_STEPS 20
#define NSEQ 131072
#define HID 192
#define ROWS 32
#define HPAD 200            // fp16 elems per LDS h-row; cols 192..194 = [x.x, x.y, 1]
#define HROWS 17            // 16 rows + zero guard row (kc6 quad over-read)
#define WOFF 147456         // frags: wout section      (3072 halfs)
#define XOFF 150528         // frags: w_ih/bias section (6144 halfs, compact q==0 layout)
#define FR_TOTAL (XOFF + 6144)

#define MFMA16(a, b, c) __builtin_amdgcn_mfma_f32_16x16x32_f16((a), (b), (c), 0, 0, 0)

// Rewrite w_hh / w_out / (w_ih,b) into MFMA B-fragment order (fp16).
// B-frag 16x16x32: lane L = q*16 + n holds k = q*8..q*8+7 of column n.
// W_hh section: [12 ht][6 kc][4 g][64 lanes][8 e]
// WX section:   [12 ht][4 g][16 n][8 e] compact — only the q==0 rows (k<8):
//               e0 = w_ih[col][0], e1 = w_ih[col][1], e2 = b_ih[col]+b_hh[col], e3..7 = 0
__global__ void build_frags(const float* __restrict__ whh,
                            const float* __restrict__ wout,
                            const float* __restrict__ wih,
                            const float* __restrict__ bih,
                            const float* __restrict__ bhh,
                            _Float16* __restrict__ dst) {
    int i = blockIdx.x * 256 + threadIdx.x;
    if (i < WOFF) {
        int e = i & 7, L = (i >> 3) & 63, g = (i >> 9) & 3, u = i >> 11;
        int kc = u % 6, ht = u / 6;
        int n = L & 15, q = L >> 4;
        dst[i] = (_Float16)whh[(size_t)(g * HID + ht * 16 + n) * HID + kc * 32 + q * 8 + e];
    } else if (i < XOFF) {
        int k = i - WOFF;
        int e = k & 7, L = (k >> 3) & 63, kc = k >> 9;
        int n = L & 15, q = L >> 4;
        dst[i] = (_Float16)((n < 2) ? wout[n * HID + kc * 32 + q * 8 + e] : 0.f);
    } else if (i < FR_TOTAL) {
        int k = i - XOFF;
        int e = k & 7, n = (k >> 3) & 15, g = (k >> 7) & 3, ht = k >> 9;
        int col = g * HID + ht * 16 + n;
        float v = 0.f;
        if (e == 0)      v = wih[col * 2];
        else if (e == 1) v = wih[col * 2 + 1];
        else if (e == 2) v = bih[col] + bhh[col];
        dst[i] = (_Float16)v;
    }
}

// 768 threads = 12 waves, 1 block/CU (LDS ~143 KB). Skewed two-half schedule;
// instruction-level MFMA/VALU interleave via sched_group_barrier. Round-6:
// round-5's read-ahead (>=1-unit lead before the consuming MFMA quartet)
// re-done inside round-3's register envelope: bx evicted to LDS (frees 16
// regs), rolling fragment window capped at 8 live frags (peak at U4).
__global__ __launch_bounds__(768) __attribute__((amdgpu_waves_per_eu(3, 3)))
void lstm_fused_kernel(
    const float* __restrict__ obs,       // [20][N][2]
    const float* __restrict__ h0,        // [N][192]
    const float* __restrict__ b_out,     // [2]
    const _Float16* __restrict__ frags,  // whh + wout + wx fragments (fp16)
    float* __restrict__ out)             // [20][N][2]
{
    __shared__ _Float16 h0b[2][HROWS][HPAD];  // rows 0..15, double-buffered (13600 B)
    __shared__ _Float16 h1b[HROWS][HPAD];     // rows 16..31, single-buffered (6800 B)
    __shared__ _Float16 b_lds[49152];         // whh kc4,kc5: [12ht][2][4g][512] (98304 B)
    __shared__ _Float16 wo_lds[3072];         // wout frags (6144 B)
    __shared__ _Float16 wx_lds[6144];         // compact x/bias frags (12288 B)
    __shared__ _Float16 wxz[512];             // zero page for quads 1..3 (1024 B)
    __shared__ float2 x_all[T_STEPS][ROWS];   // all steps' x (5120 B)

    const int tid  = threadIdx.x;
    const int wave = tid >> 6;
    const int lane = tid & 63;
    const int quad = lane >> 4;
    const int l16  = lane & 15;
    const int ht   = wave;
    const int base = blockIdx.x * ROWS;
    const int j    = ht * 16 + l16;

    const half8 HZ = {0, 0, 0, 0, 0, 0, 0, 0};

    // ---- resident weights: whh kc0..3 B-frags only (64 VGPRs) ----
    half8 bw[16];
#pragma unroll
    for (int kc = 0; kc < 4; ++kc)
#pragma unroll
        for (int g = 0; g < 4; ++g)
            bw[kc * 4 + g] = *(const half8*)&frags[(((ht * 6 + kc) * 4 + g) << 9) + lane * 8];

    // ---- staging phase A: zero h-buffers, stage kc4-5 / wout / wx / x ----
    for (int i = tid; i < 2 * HROWS * HPAD / 8; i += 768) ((half8*)h0b)[i] = HZ;
    for (int i = tid; i < HROWS * HPAD / 8; i += 768)     ((half8*)h1b)[i] = HZ;
    for (int i = tid; i < 6144; i += 768) {   // b_lds <- whh kc4,kc5
        int g = (i >> 6) & 3, u = i >> 8, k2 = u & 1, h = u >> 1;
        ((half8*)b_lds)[i] = *(const half8*)&frags[(((h * 6 + 4 + k2) * 4 + g) << 9) + (i & 63) * 8];
    }
    if (tid < 384) ((half8*)wo_lds)[tid] = *(const half8*)&frags[WOFF + tid * 8];
    ((half8*)wx_lds)[tid] = *(const half8*)&frags[XOFF + tid * 8];   // 768*8 = 6144
    if (tid < 64) ((half8*)wxz)[tid] = HZ;
    if (tid < T_STEPS * ROWS) {
        int t = tid >> 5, r = tid & 31;
        int src = (t == 0) ? 0 : (t - 1);
        x_all[t][r] = *(const float2*)&obs[((size_t)src * NSEQ + base + r) * 2];
    }
    __syncthreads();

    // ---- staging phase B: h0 -> fp16 rows; x_0; the '1' column ----
    for (int i = tid; i < ROWS * HID / 4; i += 768) {
        float4 v = *(const float4*)&h0[(size_t)base * HID + i * 4];
        int row = (i * 4) / HID, k = i * 4 - row * HID;
        _Float16* d = (row < 16) ? &h0b[0][row][k] : &h1b[row - 16][k];
        d[0] = (_Float16)v.x; d[1] = (_Float16)v.y;
        d[2] = (_Float16)v.z; d[3] = (_Float16)v.w;
    }
    if (tid < 64) {
        int row = tid >> 1;
        _Float16 v = (_Float16)((const float*)x_all[0])[tid];
        if (row < 16) h0b[0][row][192 + (tid & 1)] = v;
        else          h1b[row - 16][192 + (tid & 1)] = v;
    }
    if (tid < 16)      { h0b[0][tid][194] = (_Float16)1.f; h0b[1][tid][194] = (_Float16)1.f; }
    else if (tid < 32)   h1b[tid - 16][194] = (_Float16)1.f;
    __syncthreads();

    const float bo_n = (l16 < 2) ? b_out[l16] : 0.f;
    const _Float16* wxp = (quad == 0) ? (wx_lds + ht * 512 + l16 * 8) : wxz;

    float c[8];
#pragma unroll
    for (int i = 0; i < 8; ++i) c[i] = 0.f;

    // gate MFMAs for one 16-row half. Reads lead their consuming quartet by
    // >=1 unit; rolling window peaks at 8 live frags (32 regs, at U4):
    //   pre: ax,bx0-3,a0 | U0(MFMA ax): +a1,b40 | U1(a0): +a2,b41
    //   U2(a1): +a3,b42  | U3(a2): +a4,b43      | U4(a3): +a5,b50,b51
    //   U5(a4*b4x): +b52,b53 | U6(a5*b5x): none
    auto build = [&](const _Float16* hb, floatx4* aN) {
        const _Float16* ar  = hb + l16 * HPAD;
        const _Float16* blp = b_lds;
        const _Float16* wxr = wxp;
        asm volatile("" : "+v"(blp), "+v"(wxr));  // defeat LICM of per-step LDS reads
#pragma unroll
        for (int g = 0; g < 4; ++g) aN[g] = (floatx4){0.f, 0.f, 0.f, 0.f};

        // pre
        half8 ax  = *(const half8*)(ar + 192 + quad * 8);  // quads 1-3 over-read: B=0
        half8 bx0 = *(const half8*)(wxr + 0 * 128);
        half8 bx1 = *(const half8*)(wxr + 1 * 128);
        half8 bx2 = *(const half8*)(wxr + 2 * 128);
        half8 bx3 = *(const half8*)(wxr + 3 * 128);
        half8 a0  = *(const half8*)(ar + 0 * 32 + quad * 8);
        // U0
        half8 a1  = *(const half8*)(ar + 1 * 32 + quad * 8);
        half8 b40 = *(const half8*)&blp[(((ht * 2 + 0) * 4 + 0) << 9) + lane * 8];
        aN[0] = MFMA16(ax, bx0, aN[0]);
        aN[1] = MFMA16(ax, bx1, aN[1]);
        aN[2] = MFMA16(ax, bx2, aN[2]);
        aN[3] = MFMA16(ax, bx3, aN[3]);
        // U1
        half8 a2  = *(const half8*)(ar + 2 * 32 + quad * 8);
        half8 b41 = *(const half8*)&blp[(((ht * 2 + 0) * 4 + 1) << 9) + lane * 8];
#pragma unroll
        for (int g = 0; g < 4; ++g) aN[g] = MFMA16(a0, bw[g], aN[g]);
        // U2
        half8 a3  = *(const half8*)(ar + 3 * 32 + quad * 8);
        half8 b42 = *(const half8*)&blp[(((ht * 2 + 0) * 4 + 2) << 9) + lane * 8];
#pragma unroll
        for (int g = 0; g < 4; ++g) aN[g] = MFMA16(a1, bw[4 + g], aN[g]);
        // U3
        half8 a4  = *(const half8*)(ar + 4 * 32 + quad * 8);
        half8 b43 = *(const half8*)&blp[(((ht * 2 + 0) * 4 + 3) << 9) + lane * 8];
#pragma unroll
        for (int g = 0; g < 4; ++g) aN[g] = MFMA16(a2, bw[8 + g], aN[g]);
        // U4
        half8 a5  = *(const half8*)(ar + 5 * 32 + quad * 8);
        half8 b50 = *(const half8*)&blp[(((ht * 2 + 1) * 4 + 0) << 9) + lane * 8];
        half8 b51 = *(const half8*)&blp[(((ht * 2 + 1) * 4 + 1) << 9) + lane * 8];
#pragma unroll
        for (int g = 0; g < 4; ++g) aN[g] = MFMA16(a3, bw[12 + g], aN[g]);
        // U5
        half8 b52 = *(const half8*)&blp[(((ht * 2 + 1) * 4 + 2) << 9) + lane * 8];
        half8 b53 = *(const half8*)&blp[(((ht * 2 + 1) * 4 + 3) << 9) + lane * 8];
        aN[0] = MFMA16(a4, b40, aN[0]);
        aN[1] = MFMA16(a4, b41, aN[1]);
        aN[2] = MFMA16(a4, b42, aN[2]);
        aN[3] = MFMA16(a4, b43, aN[3]);
        // U6
        aN[0] = MFMA16(a5, b50, aN[0]);
        aN[1] = MFMA16(a5, b51, aN[1]);
        aN[2] = MFMA16(a5, b52, aN[2]);
        aN[3] = MFMA16(a5, b53, aN[3]);
    };

    // activation (rational form: 5 exp2 + 2 rcp per cell)
    auto act = [&](floatx4* aO, _Float16* hw, int cb) {
#pragma unroll
        for (int r = 0; r < 4; ++r) {
            const int row = quad * 4 + r;
            const float Ai = __builtin_amdgcn_exp2f(-1.4426950408889634f * aO[0][r]);
            const float Af = __builtin_amdgcn_exp2f(-1.4426950408889634f * aO[1][r]);
            const float Bg = __builtin_amdgcn_exp2f( 2.8853900817779268f * aO[2][r]);
            const float Co = __builtin_amdgcn_exp2f(-1.4426950408889634f * aO[3][r]);
            const float Qf = 1.f + Af;
            const float Pg = (1.f + Ai) * (Bg + 1.f);
            const float Nn = c[cb + r] * Pg + Qf * (Bg - 1.f);
            const float cn = Nn * __builtin_amdgcn_rcpf(Qf * Pg);
            c[cb + r] = cn;
            const float Dc = __builtin_amdgcn_exp2f(2.8853900817779268f * cn);
            const float hv = (Dc - 1.f) * __builtin_amdgcn_rcpf((1.f + Co) * (Dc + 1.f));
            hw[row * HPAD + j] = (_Float16)hv;
        }
    };

    // T19 pin matching build's read layout: reads sit >=1 unit (~100 cyc of
    // MFMA+VALU) ahead of their consuming quartet.
    auto sched_pattern = [&]() {
        __builtin_amdgcn_sched_group_barrier(0x100, 6, 0);   // pre: ax,bx0-3,a0
        __builtin_amdgcn_sched_group_barrier(0x002, 8, 0);   // early act VALU
#pragma unroll
        for (int u = 0; u < 4; ++u) {                        // U0..U3
            __builtin_amdgcn_sched_group_barrier(0x100, 2, 0);
            __builtin_amdgcn_sched_group_barrier(0x008, 4, 0);
            __builtin_amdgcn_sched_group_barrier(0x002, 10, 0);
        }
        __builtin_amdgcn_sched_group_barrier(0x100, 3, 0);   // U4 reads
        __builtin_amdgcn_sched_group_barrier(0x008, 4, 0);
        __builtin_amdgcn_sched_group_barrier(0x002, 10, 0);
        __builtin_amdgcn_sched_group_barrier(0x100, 2, 0);   // U5 reads
        __builtin_amdgcn_sched_group_barrier(0x008, 4, 0);
        __builtin_amdgcn_sched_group_barrier(0x002, 10, 0);
        __builtin_amdgcn_sched_group_barrier(0x008, 4, 0);   // U6
        __builtin_amdgcn_sched_group_barrier(0x002, 10, 0);
        __builtin_amdgcn_sched_group_barrier(0x200, 4, 0);   // DS_WRITE (h)
    };

    // wout for one 16-row half (wave 0 -> rows 0..15, wave 1 -> rows 16..31)
    auto wout1 = [&](int ot, const _Float16* hbase) {
        const _Float16* ar = hbase + l16 * HPAD;
        floatx4 ao = {bo_n, bo_n, bo_n, bo_n};
#pragma unroll
        for (int kc = 0; kc < 6; ++kc) {
            half8 a = *(const half8*)(ar + kc * 32 + quad * 8);
            half8 b = *(const half8*)&wo_lds[kc * 512 + lane * 8];
            ao = MFMA16(a, b, ao);
        }
        if (l16 < 2) {
#pragma unroll
            for (int r = 0; r < 4; ++r)
                out[((size_t)ot * NSEQ + base + ht * 16 + quad * 4 + r) * 2 + l16] = ao[r];
        }
    };

    // ---- prologue: accA = gates for half0 at t=0 ----
    floatx4 accA[4], accB[4];
    build(&h0b[0][0][0], accA);

    for (int t = 0; t < T_STEPS - 1; ++t) {
        _Float16* h0n = &h0b[(t + 1) & 1][0][0];

        // ===== segment X: issue H1 gate MFMAs || activation(accA) -> next H0 =====
        build(&h1b[0][0], accB);
        act(accA, h0n, 0);
        sched_pattern();
        if (ht < 2 && t > 0)
            wout1(t - 1, (ht == 0) ? &h0b[t & 1][0][0] : &h1b[0][0]);
        if (ht == 11 && lane < 32)
            h0n[(lane >> 1) * HPAD + 192 + (lane & 1)] =
                (_Float16)((const float*)x_all[t + 1])[lane];
        __syncthreads();

        // ===== segment Y: issue next-H0 gate MFMAs || activation(accB) -> H1 =====
        build(h0n, accA);
        act(accB, &h1b[0][0], 4);
        sched_pattern();
        if (ht == 11 && lane < 32)
            h1b[lane >> 1][192 + (lane & 1)] =
                (_Float16)((const float*)x_all[t + 1])[32 + lane];
        __syncthreads();
    }

    // ---- t = 19 peeled ----
    build(&h1b[0][0], accB);
    act(accA, &h0b[0][0][0], 0);
    sched_pattern();
    if (ht < 2)
        wout1(18, (ht == 0) ? &h0b[1][0][0] : &h1b[0][0]);
    __syncthreads();
    act(accB, &h1b[0][0], 4);
    __syncthreads();
    if (ht < 2)
        wout1(19, (ht == 0) ? &h0b[0][0][0] : &h1b[0][0]);
}

extern "C" void kernel_launch(void* const* d_in, const int* in_sizes, int n_in,
                              void* d_out, int out_size, void* d_ws, size_t ws_size,
                              hipStream_t stream) {
    const float* obs  = (const float*)d_in[0];
    const float* h0   = (const float*)d_in[1];
    const float* wih  = (const float*)d_in[2];
    const float* whh  = (const float*)d_in[3];
    const float* bih  = (const float*)d_in[4];
    const float* bhh  = (const float*)d_in[5];
    const float* wout = (const float*)d_in[6];
    const float* bout = (const float*)d_in[7];
    float* out = (float*)d_out;
    _Float16* frags = (_Float16*)d_ws;   // 313344 B used

    build_frags<<<(FR_TOTAL + 255) / 256, 256, 0, stream>>>(whh, wout, wih, bih, bhh, frags);
    lstm_fused_kernel<<<NSEQ / ROWS, 768, 0, stream>>>(obs, h0, bout, frags, out);
}